// Round 5
// baseline (224.093 us; speedup 1.0000x reference)
//
#include <hip/hip_runtime.h>
#include <math.h>

#define HEADS 16
#define DH    64
#define SEQ   2048
#define HID   1024
#define NROW  4096

typedef __attribute__((ext_vector_type(8))) short bf16x8;
typedef __attribute__((ext_vector_type(4))) float f32x4;

#define AS1 __attribute__((address_space(1)))
#define AS3 __attribute__((address_space(3)))

// 0.125 * log2(e): folds softmax scale and exp->exp2 into the Q pack.
#define QSCALE 0.18033688011112042f

__device__ __forceinline__ unsigned short f2bf(float x) {
    unsigned int u = __builtin_bit_cast(unsigned int, x);
    u = (u + 0x7FFFu + ((u >> 16) & 1u)) >> 16;
    return (unsigned short)u;
}

__device__ __forceinline__ void gload_lds16(const unsigned short* g, unsigned short* l) {
    __builtin_amdgcn_global_load_lds((AS1 void*)g, (AS3 void*)l, 16, 0, 0);
}

// ================= prep: conv_x + rope_tab + 2x wtrans in ONE launch =================
__device__ void wtrans_body(const float* __restrict__ wsrc, unsigned short* __restrict__ wt,
                            int K, int N, int bx, int by, float (*T)[65])
{
    const int tid = threadIdx.x;
    const int k0 = by * 64, n0 = bx * 64;
    #pragma unroll
    for (int rnd = 0; rnd < 4; ++rnd) {
        int row = (tid >> 4) + rnd * 16;
        int c = (tid & 15) * 4;
        float4 v = *(const float4*)&wsrc[(size_t)(k0 + row) * N + n0 + c];
        T[row][c] = v.x; T[row][c+1] = v.y; T[row][c+2] = v.z; T[row][c+3] = v.w;
    }
    __syncthreads();
    const int sr = tid >> 3, sc = (tid & 7) << 3;
    #pragma unroll
    for (int half = 0; half < 2; ++half) {
        int n = sr + half * 32;
        union { unsigned short u[8]; bf16x8 v; } pk;
        #pragma unroll
        for (int j = 0; j < 8; ++j) pk.u[j] = f2bf(T[sc + j][n]);
        *(bf16x8*)&wt[(size_t)(n0 + n) * K + k0 + sc] = pk.v;
    }
}

__global__ __launch_bounds__(256) void prep(const float* __restrict__ x,
                                            const float* __restrict__ rot,
                                            const float* __restrict__ w_qkv,
                                            const float* __restrict__ w_out,
                                            unsigned short* __restrict__ xb,
                                            float2* __restrict__ ctab,
                                            unsigned short* __restrict__ wqkvT,
                                            unsigned short* __restrict__ woutT)
{
    __shared__ float T[64][65];
    const int bid = blockIdx.x;
    if (bid < 2048) {
        size_t i = ((size_t)bid * 256 + threadIdx.x) * 8;
        float4 a = *(const float4*)&x[i];
        float4 b = *(const float4*)&x[i + 4];
        union { unsigned short u[8]; bf16x8 v; } pk;
        pk.u[0] = f2bf(a.x); pk.u[1] = f2bf(a.y); pk.u[2] = f2bf(a.z); pk.u[3] = f2bf(a.w);
        pk.u[4] = f2bf(b.x); pk.u[5] = f2bf(b.y); pk.u[6] = f2bf(b.z); pk.u[7] = f2bf(b.w);
        *(bf16x8*)&xb[i] = pk.v;
    } else if (bid < 2560) {
        int i = (bid - 2048) * 256 + threadIdx.x;   // SEQ*DH = 131072
        float r = rot[i];
        float s, c;
        __sincosf(r, &s, &c);
        ctab[i] = make_float2(c, s);
    } else if (bid < 3328) {
        int idx = bid - 2560;                       // 48 x 16
        wtrans_body(w_qkv, wqkvT, 1024, 3072, idx % 48, idx / 48, T);
    } else {
        int idx = bid - 3328;                       // 16 x 16
        wtrans_body(w_out, woutT, 1024, 1024, idx % 16, idx / 16, T);
    }
}

// ========== QKV GEMM (global_load_lds staging) with fused RoPE/split/V^T epilogue ==========
__global__ __launch_bounds__(256) void gemm_qkv(const unsigned short* __restrict__ A,
                                                const unsigned short* __restrict__ Bt,
                                                const float2* __restrict__ ctab,
                                                unsigned short* __restrict__ qb,
                                                unsigned short* __restrict__ kb,
                                                unsigned short* __restrict__ vt)
{
    __shared__ __align__(16) unsigned short As[128 * 32];
    __shared__ __align__(16) unsigned short Bs[128 * 32];
    const int tid = threadIdx.x;
    const int w = tid >> 6, lane = tid & 63;
    const int quad = lane >> 4, lm = lane & 15;
    const int wr = (w >> 1) * 64, wc = (w & 1) * 64;
    const int bm = blockIdx.y * 128, bn = blockIdx.x * 128;
    const int m0 = tid >> 2;
    const int sk = (tid & 3) << 3;

    f32x4 acc[4][4];
    #pragma unroll
    for (int i = 0; i < 4; ++i)
        #pragma unroll
        for (int j = 0; j < 4; ++j) acc[i][j] = (f32x4){0.f, 0.f, 0.f, 0.f};

    for (int k0 = 0; k0 < 1024; k0 += 32) {
        __syncthreads();
        gload_lds16(&A [(size_t)(bm + m0     ) * 1024 + k0 + sk], As + (size_t)w * 512);
        gload_lds16(&A [(size_t)(bm + m0 + 64) * 1024 + k0 + sk], As + 2048 + (size_t)w * 512);
        gload_lds16(&Bt[(size_t)(bn + m0     ) * 1024 + k0 + sk], Bs + (size_t)w * 512);
        gload_lds16(&Bt[(size_t)(bn + m0 + 64) * 1024 + k0 + sk], Bs + 2048 + (size_t)w * 512);
        __syncthreads();
        bf16x8 af[4], bfr[4];
        #pragma unroll
        for (int mt = 0; mt < 4; ++mt) af[mt] = *(const bf16x8*)&As[(wr + mt * 16 + lm) * 32 + quad * 8];
        #pragma unroll
        for (int nt = 0; nt < 4; ++nt) bfr[nt] = *(const bf16x8*)&Bs[(wc + nt * 16 + lm) * 32 + quad * 8];
        #pragma unroll
        for (int mt = 0; mt < 4; ++mt)
            #pragma unroll
            for (int nt = 0; nt < 4; ++nt)
                acc[mt][nt] = __builtin_amdgcn_mfma_f32_16x16x32_bf16(af[mt], bfr[nt], acc[mt][nt], 0, 0, 0);
    }

    const int colbase = bn + wc;
    const int region = colbase >> 10;      // 0=q, 1=k, 2=v
    const int h = (colbase >> 6) & 15;

    if (region == 2) {
        #pragma unroll
        for (int mt = 0; mt < 4; ++mt) {
            int rowb = bm + wr + mt * 16 + quad * 4;
            int b = rowb >> 11, seq = rowb & (SEQ - 1);
            #pragma unroll
            for (int nt = 0; nt < 4; ++nt) {
                int d = nt * 16 + lm;
                ushort4 pk;
                pk.x = f2bf(acc[mt][nt][0]); pk.y = f2bf(acc[mt][nt][1]);
                pk.z = f2bf(acc[mt][nt][2]); pk.w = f2bf(acc[mt][nt][3]);
                *(ushort4*)&vt[((size_t)(b * HEADS + h) * DH + d) * SEQ + seq] = pk;
            }
        }
    } else {
        const float qs = (region == 0) ? QSCALE : 1.0f;
        unsigned short* dst = (region == 0) ? qb : kb;
        #pragma unroll
        for (int mt = 0; mt < 4; ++mt) {
            #pragma unroll
            for (int nt = 0; nt < 2; ++nt) {
                int d = nt * 16 + lm;
                #pragma unroll
                for (int r = 0; r < 4; ++r) {
                    int row = bm + wr + mt * 16 + quad * 4 + r;
                    int b = row >> 11, seq = row & (SEQ - 1);
                    float2 cs0 = ctab[seq * DH + d];
                    float2 cs1 = ctab[seq * DH + d + 32];
                    float x0 = acc[mt][nt][r];
                    float x1 = acc[mt][nt + 2][r];
                    size_t ob = ((size_t)(b * HEADS + h) * SEQ + seq) * DH;
                    dst[ob + d]      = f2bf((x0 * cs0.x - x1 * cs0.y) * qs);
                    dst[ob + d + 32] = f2bf((x1 * cs1.x + x0 * cs1.y) * qs);
                }
            }
        }
    }
}

// ========== Flash attention v4: 64 q/wave, K/V frags direct from global, ==========
// ========== barrier-free k-loop, P-only LDS, 4-way K-split merge         ==========
// block = 256 thr = 4 waves; wave w = k-group w (kseq [w*512, w*512+512)), all waves
// share the block's 64 q rows. grid (SEQ/64, BSZ*HEADS).
#define PSW 36
#define OPW 68
__global__ __launch_bounds__(256) void attn4(const unsigned short* __restrict__ qb,
                                             const unsigned short* __restrict__ kb,
                                             const unsigned short* __restrict__ vt,
                                             unsigned short* __restrict__ attnb)
{
    __shared__ __align__(16) char smem[4 * 64 * PSW * 2];   // 18432 B
    unsigned short* Ps   = (unsigned short*)smem;           // [4 waves][64 q][PSW]
    float*          oBuf = (float*)smem;                    // merge overlay [64][OPW] = 17408 B
    float*          lRed = (float*)(smem + 17408);          // [3][64] = 768 B

    const int tid = threadIdx.x;
    const int w = tid >> 6, lane = tid & 63, quad = lane >> 4, lm = lane & 15;
    const int bh = blockIdx.y, q0 = blockIdx.x * 64;
    const int b = bh >> 4, h = bh & 15;
    const size_t hb = (size_t)bh * SEQ * DH;   // also valid base for vt [bh][64][2048]
    unsigned short* myPs = Ps + w * (64 * PSW);

    // Q fragments in registers: q = qt*16+lm, d = c*32 + quad*8 + j
    bf16x8 qf[4][2];
    #pragma unroll
    for (int qt = 0; qt < 4; ++qt)
        #pragma unroll
        for (int c = 0; c < 2; ++c)
            qf[qt][c] = *(const bf16x8*)&qb[hb + (size_t)(q0 + qt * 16 + lm) * DH + c * 32 + quad * 8];

    float rs[4] = {0.f, 0.f, 0.f, 0.f};
    f32x4 o[4][4];   // [qt][dt]
    #pragma unroll
    for (int qt = 0; qt < 4; ++qt)
        #pragma unroll
        for (int dt = 0; dt < 4; ++dt) o[qt][dt] = (f32x4){0.f, 0.f, 0.f, 0.f};

    const int kstart = w * 512;
    for (int it = 0; it < 16; ++it) {
        const int kbase = kstart + it * 32;
        // K A-frags direct from global: row kseq = kbase + kt*16 + lm, k = c*32 + quad*8 + j
        bf16x8 kf[2][2];
        #pragma unroll
        for (int kt = 0; kt < 2; ++kt)
            #pragma unroll
            for (int c = 0; c < 2; ++c)
                kf[kt][c] = *(const bf16x8*)&kb[hb + (size_t)(kbase + kt * 16 + lm) * DH + c * 32 + quad * 8];
        // V B-frags direct from global vt[bh][d][seq]: col d = dt*16+lm, k = quad*8 + j
        bf16x8 vf[4];
        #pragma unroll
        for (int dt = 0; dt < 4; ++dt)
            vf[dt] = *(const bf16x8*)&vt[hb + (size_t)(dt * 16 + lm) * SEQ + kbase + quad * 8];

        // S^T = K Q^T  (C: col q = lm, row kseq = kt*16 + quad*4 + r)
        #pragma unroll
        for (int kt = 0; kt < 2; ++kt) {
            f32x4 s[4];
            #pragma unroll
            for (int qt = 0; qt < 4; ++qt) {
                f32x4 z = (f32x4){0.f, 0.f, 0.f, 0.f};
                z = __builtin_amdgcn_mfma_f32_16x16x32_bf16(kf[kt][0], qf[qt][0], z, 0, 0, 0);
                s[qt] = __builtin_amdgcn_mfma_f32_16x16x32_bf16(kf[kt][1], qf[qt][1], z, 0, 0, 0);
            }
            #pragma unroll
            for (int qt = 0; qt < 4; ++qt) {
                unsigned int u[4];
                #pragma unroll
                for (int r = 0; r < 4; ++r) {
                    float p = __builtin_amdgcn_exp2f(s[qt][r]);
                    unsigned int pu = __builtin_bit_cast(unsigned int, p) & 0xFFFF0000u;
                    rs[qt] += __builtin_bit_cast(float, pu);
                    u[r] = pu;
                }
                unsigned int lo = __builtin_amdgcn_perm(u[1], u[0], 0x07060302);
                unsigned int hi = __builtin_amdgcn_perm(u[3], u[2], 0x07060302);
                unsigned long long pv = ((unsigned long long)hi << 32) | lo;
                *(unsigned long long*)&myPs[(qt * 16 + lm) * PSW + kt * 16 + quad * 4] = pv;
            }
        }
        // O += P V  (A = P[q][k32] from LDS, B = vf)
        #pragma unroll
        for (int qt = 0; qt < 4; ++qt) {
            bf16x8 pf = *(const bf16x8*)&myPs[(qt * 16 + lm) * PSW + quad * 8];
            #pragma unroll
            for (int dt = 0; dt < 4; ++dt)
                o[qt][dt] = __builtin_amdgcn_mfma_f32_16x16x32_bf16(pf, vf[dt], o[qt][dt], 0, 0, 0);
        }
    }

    // reduce rs across quads (value for q = qt*16+lm replicated to all quads)
    #pragma unroll
    for (int off = 16; off < 64; off <<= 1)
        #pragma unroll
        for (int qt = 0; qt < 4; ++qt) rs[qt] += __shfl_xor(rs[qt], off, 64);

    // merge the 4 k-groups: l first, then O in 3 rounds through LDS
    __syncthreads();
    if (w > 0 && quad == 0) {
        #pragma unroll
        for (int qt = 0; qt < 4; ++qt) lRed[(w - 1) * 64 + qt * 16 + lm] = rs[qt];
    }
    __syncthreads();
    if (w == 0) {
        #pragma unroll
        for (int qt = 0; qt < 4; ++qt)
            rs[qt] += lRed[qt * 16 + lm] + lRed[64 + qt * 16 + lm] + lRed[128 + qt * 16 + lm];
    }
    #pragma unroll
    for (int s = 1; s < 4; ++s) {
        __syncthreads();
        if (w == s) {
            #pragma unroll
            for (int qt = 0; qt < 4; ++qt)
                #pragma unroll
                for (int dt = 0; dt < 4; ++dt)
                    #pragma unroll
                    for (int r = 0; r < 4; ++r)
                        oBuf[(qt * 16 + quad * 4 + r) * OPW + dt * 16 + lm] = o[qt][dt][r];
        }
        __syncthreads();
        if (w == 0) {
            #pragma unroll
            for (int qt = 0; qt < 4; ++qt)
                #pragma unroll
                for (int dt = 0; dt < 4; ++dt)
                    #pragma unroll
                    for (int r = 0; r < 4; ++r)
                        o[qt][dt][r] += oBuf[(qt * 16 + quad * 4 + r) * OPW + dt * 16 + lm];
        }
    }
    if (w == 0) {
        #pragma unroll
        for (int qt = 0; qt < 4; ++qt)
            #pragma unroll
            for (int r = 0; r < 4; ++r) {
                float inv = 1.0f / __shfl(rs[qt], quad * 4 + r, 64);
                int row = b * SEQ + q0 + qt * 16 + quad * 4 + r;
                #pragma unroll
                for (int dt = 0; dt < 4; ++dt)
                    attnb[(size_t)row * HID + h * DH + dt * 16 + lm] = f2bf(o[qt][dt][r] * inv);
            }
    }
}

// ========== output GEMM: 64x128 tiles for 2x grid (occupancy) ==========
__global__ __launch_bounds__(256) void gemm_out(const unsigned short* __restrict__ A,
                                                const unsigned short* __restrict__ Bt,
                                                float* __restrict__ C)
{
    __shared__ __align__(16) unsigned short As[64 * 32];
    __shared__ __align__(16) unsigned short Bs[128 * 32];
    const int tid = threadIdx.x;
    const int w = tid >> 6, lane = tid & 63;
    const int quad = lane >> 4, lm = lane & 15;
    const int wr = (w >> 1) * 32, wc = (w & 1) * 64;
    const int bm = blockIdx.y * 64, bn = blockIdx.x * 128;
    const int m0 = tid >> 2;
    const int sk = (tid & 3) << 3;

    f32x4 acc[2][4];
    #pragma unroll
    for (int i = 0; i < 2; ++i)
        #pragma unroll
        for (int j = 0; j < 4; ++j) acc[i][j] = (f32x4){0.f, 0.f, 0.f, 0.f};

    for (int k0 = 0; k0 < 1024; k0 += 32) {
        __syncthreads();
        gload_lds16(&A [(size_t)(bm + m0     ) * 1024 + k0 + sk], As + (size_t)w * 512);
        gload_lds16(&Bt[(size_t)(bn + m0     ) * 1024 + k0 + sk], Bs + (size_t)w * 512);
        gload_lds16(&Bt[(size_t)(bn + m0 + 64) * 1024 + k0 + sk], Bs + 2048 + (size_t)w * 512);
        __syncthreads();
        bf16x8 af[2], bfr[4];
        #pragma unroll
        for (int mt = 0; mt < 2; ++mt) af[mt] = *(const bf16x8*)&As[(wr + mt * 16 + lm) * 32 + quad * 8];
        #pragma unroll
        for (int nt = 0; nt < 4; ++nt) bfr[nt] = *(const bf16x8*)&Bs[(wc + nt * 16 + lm) * 32 + quad * 8];
        #pragma unroll
        for (int mt = 0; mt < 2; ++mt)
            #pragma unroll
            for (int nt = 0; nt < 4; ++nt)
                acc[mt][nt] = __builtin_amdgcn_mfma_f32_16x16x32_bf16(af[mt], bfr[nt], acc[mt][nt], 0, 0, 0);
    }

    #pragma unroll
    for (int mt = 0; mt < 2; ++mt)
        #pragma unroll
        for (int nt = 0; nt < 4; ++nt) {
            int col = bn + wc + nt * 16 + lm;
            #pragma unroll
            for (int r = 0; r < 4; ++r) {
                int row = bm + wr + mt * 16 + quad * 4 + r;
                C[(size_t)row * 1024 + col] = acc[mt][nt][r];
            }
        }
}

extern "C" void kernel_launch(void* const* d_in, const int* in_sizes, int n_in,
                              void* d_out, int out_size, void* d_ws, size_t ws_size,
                              hipStream_t stream) {
    const float* x     = (const float*)d_in[0];
    const float* rot   = (const float*)d_in[1];
    const float* w_qkv = (const float*)d_in[2];
    const float* w_out = (const float*)d_in[3];
    float* out = (float*)d_out;

    char* ws = (char*)d_ws;
    unsigned short* xb    = (unsigned short*)(ws);                         // 8 MB
    unsigned short* qb    = (unsigned short*)(ws + (size_t)( 8u << 20));   // 8 MB [bh][seq][64]
    unsigned short* kb    = (unsigned short*)(ws + (size_t)(16u << 20));   // 8 MB [bh][seq][64]
    unsigned short* vt    = (unsigned short*)(ws + (size_t)(24u << 20));   // 8 MB [bh][64][seq]
    unsigned short* attnb = (unsigned short*)(ws + (size_t)(32u << 20));   // 8 MB
    unsigned short* wqkvT = (unsigned short*)(ws + (size_t)(40u << 20));   // 6 MB
    unsigned short* woutT = (unsigned short*)(ws + (size_t)(46u << 20));   // 2 MB
    float2*         ctab  = (float2*)        (ws + (size_t)(48u << 20));   // 1 MB

    prep<<<3584, 256, 0, stream>>>(x, rot, w_qkv, w_out, xb, ctab, wqkvT, woutT);

    gemm_qkv<<<dim3(24, 32), 256, 0, stream>>>(xb, wqkvT, ctab, qb, kb, vt);

    attn4<<<dim3(SEQ / 64, 32), 256, 0, stream>>>(qb, kb, vt, attnb);

    gemm_out<<<dim3(8, 64), 256, 0, stream>>>(attnb, woutT, out);
}